// Round 6
// baseline (196.620 us; speedup 1.0000x reference)
//
#include <hip/hip_runtime.h>
#include <math.h>

// Problem constants (B=16, T=2, H=384, W=640)
#define NB   16
#define HW_  245760          // H*W
#define THW_ 491520          // 2*H*W
#define CAP  2048            // per-batch conservative compaction capacity (~1440 used)
#define BIGF 1e30f
#define DELTAF 0.03f
#define H1SLICES 8           // global L1-histogram slices (contention relief)

// ---- workspace layout (bytes) ----
#define SUMS_OFF   0u                                   // double[16*5]
#define HIST1_OFF  1024u                                // uint[16*8*4096] sliced
#define HIST2_OFF  (HIST1_OFF + NB*H1SLICES*4096u*4u)   // uint[16*4*4096]
#define CNT_OFF    (HIST2_OFF + NB*4u*4096u*4u)         // uint[16*64] (256B padded per batch)
#define DONE_OFF   (CNT_OFF + NB*256u)                  // uint[1] k6 completion counter
#define ZERO_BYTES (DONE_OFF + 64u)
#define PAR_OFF    ((ZERO_BYTES + 255u) & ~255u)
#define S_OFF      (PAR_OFF + 0u)      // float[16]
#define T_OFF      (PAR_OFF + 64u)     // float[16]
#define RR_OFF     (PAR_OFF + 128u)    // float[16]
#define NN_OFF     (PAR_OFF + 320u)    // int[16]
#define BIN_OFF    (PAR_OFF + 384u)    // int[16*4]
#define RK_OFF     (PAR_OFF + 640u)    // uint[16*4]
#define FR_OFF     (PAR_OFF + 896u)    // float[16*2]
#define LD_OFF     (PAR_OFF + 1024u)   // float[16]
#define LA_OFF     (PAR_OFF + 1088u)   // float[16]
#define THUB_OFF   (PAR_OFF + 1152u)   // float[16] conservative th upper bound
#define BUFD_OFF   (PAR_OFF + 2048u)   // float[16*CAP] |dpred-dgt|
#define BUFA_OFF   (BUFD_OFF + NB*CAP*4u)   // float[16*CAP] |dpred-prev|
#define BUFG_OFF   (BUFA_OFF + NB*CAP*4u)   // float[16*CAP] |dgt|

#define WS_SUMS(ws) ((double*)((ws) + SUMS_OFF))
#define WS_H1(ws)   ((unsigned*)((ws) + HIST1_OFF))
#define WS_H2(ws)   ((unsigned*)((ws) + HIST2_OFF))
#define WS_CNT(ws)  ((unsigned*)((ws) + CNT_OFF))      // index b*64
#define WS_DONE(ws) ((unsigned*)((ws) + DONE_OFF))
#define WS_S(ws)    ((float*)((ws) + S_OFF))
#define WS_T(ws)    ((float*)((ws) + T_OFF))
#define WS_RR(ws)   ((float*)((ws) + RR_OFF))
#define WS_NN(ws)   ((int*)((ws) + NN_OFF))
#define WS_BIN(ws)  ((int*)((ws) + BIN_OFF))
#define WS_RK(ws)   ((unsigned*)((ws) + RK_OFF))
#define WS_FR(ws)   ((float*)((ws) + FR_OFF))
#define WS_LD(ws)   ((float*)((ws) + LD_OFF))
#define WS_LA(ws)   ((float*)((ws) + LA_OFF))
#define WS_THUB(ws) ((float*)((ws) + THUB_OFF))
#define WS_BUFD(ws) ((float*)((ws) + BUFD_OFF))
#define WS_BUFA(ws) ((float*)((ws) + BUFA_OFF))
#define WS_BUFG(ws) ((float*)((ws) + BUFG_OFF))

// order-preserving float<->uint key
__device__ __forceinline__ unsigned fkey(float x) {
    unsigned u = __float_as_uint(x);
    return (u & 0x80000000u) ? ~u : (u | 0x80000000u);
}
__device__ __forceinline__ float keyf(unsigned k) {
    unsigned u = (k & 0x80000000u) ? (k & 0x7fffffffu) : ~k;
    return __uint_as_float(u);
}

// Block-cooperative rank locate in a 4096-bin histogram (256 threads).
__device__ void locate_ranks(const unsigned* __restrict__ hist, unsigned* part,
                             const int* ranks, int nr, int* outBin, unsigned* outOff) {
    int tid = threadIdx.x;
    int base = tid * 16;
    unsigned hloc[16];
    unsigned csum = 0;
#pragma unroll
    for (int j = 0; j < 16; j++) { hloc[j] = hist[base + j]; csum += hloc[j]; }
    part[tid] = csum;
    __syncthreads();
    for (int d = 1; d < 256; d <<= 1) {
        unsigned add = (tid >= d) ? part[tid - d] : 0u;
        __syncthreads();
        part[tid] += add;
        __syncthreads();
    }
    unsigned incl = part[tid];
    unsigned excl = incl - csum;
    for (int q = 0; q < nr; q++) {
        int r = ranks[q];
        if (r >= (int)excl && r < (int)incl) {
            unsigned cum = excl;
#pragma unroll
            for (int j = 0; j < 16; j++) {
                unsigned h = hloc[j];
                if ((unsigned)r < cum + h) { outBin[q] = base + j; outOff[q] = (unsigned)r - cum; break; }
                cum += h;
            }
        }
    }
    __syncthreads();
}

// K1: per-batch regression sums (f64) + level-1 (top-12-bit) histogram of masked gt.
// grid (60, 16): 8192 elements/block.
// LDS hist: 2 half-wave-private interleaved copies (bin*2 + lane>>5) -> halves
// same-address serialization within a wave64 ds_atomic.
// Global H1: 8 slices by blockIdx.x&7 -> ~8x less cacheline contention at flush.
__global__ __launch_bounds__(256) void k1_sums_hist(const float* __restrict__ pred,
                                                    const float* __restrict__ gt,
                                                    const float* __restrict__ mask,
                                                    unsigned char* ws) {
    __shared__ unsigned hist[8192];
    __shared__ double red[4][5];
    int tid = threadIdx.x;
    int b = blockIdx.y;
    unsigned half = (tid >> 5) & 1u;
    for (int i = tid; i < 8192; i += 256) hist[i] = 0;
    __syncthreads();

    size_t base = (size_t)b * THW_ + (size_t)blockIdx.x * 8192 + (size_t)tid * 4;
    double a00 = 0, a01 = 0, a11 = 0, sb0 = 0, sb1 = 0;
    float4 pc = *(const float4*)(pred + base);
    float4 gc = *(const float4*)(gt + base);
    float4 mc = *(const float4*)(mask + base);
#pragma unroll
    for (int it = 0; it < 8; it++) {
        float4 pn, gn, mn;
        if (it < 7) {
            size_t idx = base + (size_t)(it + 1) * 1024;
            pn = *(const float4*)(pred + idx);
            gn = *(const float4*)(gt + idx);
            mn = *(const float4*)(mask + idx);
        }
        float pa[4] = {pc.x, pc.y, pc.z, pc.w};
        float ga[4] = {gc.x, gc.y, gc.z, gc.w};
        float ma[4] = {mc.x, mc.y, mc.z, mc.w};
#pragma unroll
        for (int c = 0; c < 4; c++) {
            if (ma[c] > 0.5f) {
                float pv = pa[c], gv = ga[c];
                a00 += (double)(pv * pv);
                a01 += (double)pv;
                a11 += 1.0;
                sb0 += (double)(pv * gv);
                sb1 += (double)gv;
                atomicAdd(&hist[((fkey(gv) >> 20) << 1) | half], 1u);
            }
        }
        pc = pn; gc = gn; mc = mn;
    }
    __syncthreads();
    // flush nonzero bins to this block's slice, start rotated to spread lines
    unsigned* gh = WS_H1(ws) + ((size_t)b * H1SLICES + (blockIdx.x & (H1SLICES - 1))) * 4096u;
    unsigned rot = (blockIdx.x * 331u) & 4095u;
    for (int i = tid; i < 4096; i += 256) {
        int bin = (int)(((unsigned)i + rot) & 4095u);
        unsigned v = hist[bin * 2] + hist[bin * 2 + 1];
        if (v) atomicAdd(&gh[bin], v);
    }
    int lane = tid & 63, wid = tid >> 6;
    double acc[5] = {a00, a01, a11, sb0, sb1};
#pragma unroll
    for (int j = 0; j < 5; j++) {
        double v = acc[j];
        for (int off = 32; off > 0; off >>= 1) v += __shfl_down(v, off);
        if (lane == 0) red[wid][j] = v;
    }
    __syncthreads();
    if (tid == 0) {
        double* gs = WS_SUMS(ws) + b * 5;
#pragma unroll
        for (int j = 0; j < 5; j++)
            atomicAdd(&gs[j], red[0][j] + red[1][j] + red[2][j] + red[3][j]);
    }
}

// K2: per-batch: s,t; sum the 8 H1 slices into LDS; quantile ranks; L1 bins; th_ub.
__global__ __launch_bounds__(256) void k2_rank1(unsigned char* ws) {
    __shared__ unsigned hsum[4096];
    __shared__ unsigned part[256];
    int b = blockIdx.x, tid = threadIdx.x;
    const double* gs = WS_SUMS(ws) + b * 5;
    double a00 = gs[0], a01 = gs[1], a11 = gs[2], b0 = gs[3], b1 = gs[4];
    int n = (int)(a11 + 0.5);
    if (tid == 0) {
        double det = a00 * a11 - a01 * a01;
        double x0 = 0.0, x1 = 0.0;
        if (det != 0.0) {
            x0 = (a11 * b0 - a01 * b1) / (det + 1e-6);
            x1 = (-a01 * b0 + a00 * b1) / (det + 1e-6);
        }
        WS_S(ws)[b] = (float)x0;
        WS_T(ws)[b] = (float)x1;
        WS_NN(ws)[b] = n;
    }
    // reduce slices: thread t owns bins [t*16, t*16+16)
    {
        const unsigned* h1 = WS_H1(ws) + (size_t)b * H1SLICES * 4096u;
        int base = tid * 16;
        unsigned acc[16];
#pragma unroll
        for (int j = 0; j < 16; j++) acc[j] = 0;
        for (int s = 0; s < H1SLICES; s++) {
            const unsigned* hs = h1 + (size_t)s * 4096u + base;
#pragma unroll
            for (int j = 0; j < 16; j++) acc[j] += hs[j];
        }
#pragma unroll
        for (int j = 0; j < 16; j++) hsum[base + j] = acc[j];
    }
    __syncthreads();
    float nm1 = (float)((n - 1 > 0) ? (n - 1) : 0);
    float p05 = 0.05f * nm1, p95 = 0.95f * nm1;   // f32 to match JAX weak-type promotion
    int ranks[4] = {(int)floorf(p05), (int)ceilf(p05), (int)floorf(p95), (int)ceilf(p95)};
    float f05 = p05 - floorf(p05), f95 = p95 - floorf(p95);
    if (tid == 0) {
        WS_FR(ws)[b * 2 + 0] = f05;
        WS_FR(ws)[b * 2 + 1] = f95;
    }
    if (n > 0) {
        locate_ranks(hsum, part, ranks, 4, WS_BIN(ws) + b * 4, WS_RK(ws) + b * 4);
        if (tid == 0) {
            const int* bp = WS_BIN(ws) + b * 4;
            float lb0 = keyf(((unsigned)bp[0]) << 20), ub0 = keyf((((unsigned)bp[0]) << 20) | 0xFFFFFu);
            float lb1 = keyf(((unsigned)bp[1]) << 20), ub1 = keyf((((unsigned)bp[1]) << 20) | 0xFFFFFu);
            float lb2 = keyf(((unsigned)bp[2]) << 20), ub2 = keyf((((unsigned)bp[2]) << 20) | 0xFFFFFu);
            float lb3 = keyf(((unsigned)bp[3]) << 20), ub3 = keyf((((unsigned)bp[3]) << 20) | 0xFFFFFu);
            float qlo_lb = (1.0f - f05) * lb0 + f05 * lb1;
            float qlo_ub = (1.0f - f05) * ub0 + f05 * ub1;
            float qhi_lb = (1.0f - f95) * lb2 + f95 * lb3;
            float qhi_ub = (1.0f - f95) * ub2 + f95 * ub3;
            float rr_ub = fmaxf(qhi_ub - qlo_lb, 1e-6f);
            if (qhi_lb - qlo_ub <= 0.0f) rr_ub = fmaxf(rr_ub, 1.0f);
            WS_THUB(ws)[b] = 0.01f * rr_ub * 1.0001f;   // tiny safety margin
        }
    } else if (tid == 0) {
        WS_THUB(ws)[b] = 0.0f;   // no masked pixels -> nothing static
        int* bp = WS_BIN(ws) + b * 4;
        bp[0] = bp[1] = bp[2] = bp[3] = -1;
    }
}

// K5: elementwise: dpred (-> curr_grad), conservative compact (numerators + |dgt|),
// and fused L2-histogram population for the 4 selected L1 bins (both frames).
// grid (240, 16), block 256; 1024 pixels per block.
__global__ __launch_bounds__(256) void k5_elem(const float* __restrict__ pred,
                                               const float* __restrict__ gt,
                                               const float* __restrict__ mask,
                                               const float* __restrict__ prev,
                                               float* __restrict__ out,
                                               unsigned char* ws) {
    __shared__ unsigned lcnt;
    __shared__ unsigned gbase;
    int b = blockIdx.y, tid = threadIdx.x;
    if (tid == 0) lcnt = 0;
    float s = WS_S(ws)[b], t = WS_T(ws)[b], thub = WS_THUB(ws)[b];
    const int* bp = WS_BIN(ws) + b * 4;
    int bn0 = bp[0], bn1 = bp[1], bn2 = bp[2], bn3 = bp[3];
    unsigned* h2 = WS_H2(ws);
    size_t hw = (size_t)blockIdx.x * 1024 + (size_t)tid * 4;
    size_t i0 = (size_t)b * THW_ + hw;
    size_t i1 = i0 + HW_;
    size_t ip = (size_t)b * HW_ + hw;
    float4 p0 = *(const float4*)(pred + i0);
    float4 p1 = *(const float4*)(pred + i1);
    float4 g0 = *(const float4*)(gt + i0);
    float4 g1 = *(const float4*)(gt + i1);
    float4 m0 = *(const float4*)(mask + i0);
    float4 m1 = *(const float4*)(mask + i1);
    float4 pv = *(const float4*)(prev + ip);
    float p0c[4] = {p0.x, p0.y, p0.z, p0.w};
    float p1c[4] = {p1.x, p1.y, p1.z, p1.w};
    float g0c[4] = {g0.x, g0.y, g0.z, g0.w};
    float g1c[4] = {g1.x, g1.y, g1.z, g1.w};
    float m0c[4] = {m0.x, m0.y, m0.z, m0.w};
    float m1c[4] = {m1.x, m1.y, m1.z, m1.w};
    float pvc[4] = {pv.x, pv.y, pv.z, pv.w};
    float dp[4], rd[4], ra[4], rg[4];
    int nst = 0;
    __syncthreads();   // lcnt=0 visible
#pragma unroll
    for (int c = 0; c < 4; c++) {
        float pa1 = s * p1c[c] + t;
        float pa0 = s * p0c[c] + t;
        float d = pa1 - pa0;
        dp[c] = d;
        float dg = g1c[c] - g0c[c];
        float adg = fabsf(dg);
        bool msk0 = m0c[c] > 0.5f, msk1 = m1c[c] > 0.5f;
        if (msk0 && msk1 && adg < thub) {
            rd[nst] = fabsf(d - dg);
            ra[nst] = fabsf(d - pvc[c]);
            rg[nst] = adg;
            nst++;
        }
        if (msk0) {
            unsigned key = fkey(g0c[c]);
            int top = (int)(key >> 20);
            unsigned sub = (key >> 8) & 0xFFFu;
            if (top == bn0) atomicAdd(&h2[(((size_t)b * 4 + 0) << 12) + sub], 1u);
            if (top == bn1) atomicAdd(&h2[(((size_t)b * 4 + 1) << 12) + sub], 1u);
            if (top == bn2) atomicAdd(&h2[(((size_t)b * 4 + 2) << 12) + sub], 1u);
            if (top == bn3) atomicAdd(&h2[(((size_t)b * 4 + 3) << 12) + sub], 1u);
        }
        if (msk1) {
            unsigned key = fkey(g1c[c]);
            int top = (int)(key >> 20);
            unsigned sub = (key >> 8) & 0xFFFu;
            if (top == bn0) atomicAdd(&h2[(((size_t)b * 4 + 0) << 12) + sub], 1u);
            if (top == bn1) atomicAdd(&h2[(((size_t)b * 4 + 1) << 12) + sub], 1u);
            if (top == bn2) atomicAdd(&h2[(((size_t)b * 4 + 2) << 12) + sub], 1u);
            if (top == bn3) atomicAdd(&h2[(((size_t)b * 4 + 3) << 12) + sub], 1u);
        }
    }
    unsigned myoff = 0;
    if (nst) myoff = atomicAdd(&lcnt, (unsigned)nst);   // LDS atomic — cheap
    __syncthreads();
    if (tid == 0 && lcnt > 0) gbase = atomicAdd(&WS_CNT(ws)[b * 64], lcnt);
    __syncthreads();
    if (nst) {
        float* bufd = WS_BUFD(ws) + (size_t)b * CAP;
        float* bufa = WS_BUFA(ws) + (size_t)b * CAP;
        float* bufg = WS_BUFG(ws) + (size_t)b * CAP;
        unsigned base0 = gbase + myoff;
        for (int j = 0; j < nst; j++) {
            unsigned pos = base0 + (unsigned)j;
            if (pos < CAP) { bufd[pos] = rd[j]; bufa[pos] = ra[j]; bufg[pos] = rg[j]; }
        }
    }
    float4 dout = make_float4(dp[0], dp[1], dp[2], dp[3]);
    *(float4*)(out + 4 + ip) = dout;
}

// K6: per (batch, which): exact rr from H2, exact-th filter, trimmed-Huber via
// 3-level radix select. Last block (completion counter) writes the 4 scalars.
// grid (2, 16), block 256.
__global__ __launch_bounds__(256) void k6_huber(float* __restrict__ out, unsigned char* ws) {
    __shared__ float v[CAP];
    __shared__ unsigned hist[4096];
    __shared__ unsigned part[256];
    __shared__ int ssub[4];
    __shared__ unsigned wtot[4];
    __shared__ unsigned sSel;
    __shared__ unsigned sRank;
    __shared__ float redf[4];
    __shared__ unsigned redc[4];
    __shared__ unsigned lk;
    int which = blockIdx.x, b = blockIdx.y, tid = threadIdx.x;
    int lane = tid & 63, wid = tid >> 6;
    const float* bufN = (which ? WS_BUFA(ws) : WS_BUFD(ws)) + (size_t)b * CAP;
    const float* bufG = WS_BUFG(ws) + (size_t)b * CAP;
    float* lout = which ? WS_LA(ws) : WS_LD(ws);

    // ---- exact quantile -> rr/th/sc (both which-blocks compute identically)
    int nmask = WS_NN(ws)[b];
    if (nmask > 0) {
        for (int q = 0; q < 4; q++) {
            int rq[1] = {(int)WS_RK(ws)[b * 4 + q]};
            unsigned dummyOff[1];
            locate_ranks(WS_H2(ws) + (((size_t)b * 4 + q) << 12), part, rq, 1, ssub + q, dummyOff);
        }
    }
    __syncthreads();
    float rr, th, sc;
    {
        float vals[4] = {0.f, 0.f, 0.f, 0.f};
        if (nmask > 0) {
            for (int q = 0; q < 4; q++) {
                unsigned key = (((unsigned)WS_BIN(ws)[b * 4 + q]) << 20) |
                               (((unsigned)ssub[q]) << 8) | 0x80u;   // mid of 256-ulp slot
                vals[q] = keyf(key);
            }
        }
        float f05 = WS_FR(ws)[b * 2 + 0], f95 = WS_FR(ws)[b * 2 + 1];
        float qlo = vals[0] + (vals[1] - vals[0]) * f05;
        float qhi = vals[2] + (vals[3] - vals[2]) * f95;
        bool valid = (nmask > 0) && isfinite(qlo) && isfinite(qhi) && (qhi - qlo > 0.0f) &&
                     (fabsf(qlo) < BIGF) && (fabsf(qhi) < BIGF);
        rr = valid ? fmaxf(qhi - qlo, 1e-6f) : 1.0f;
        th = 0.01f * rr;           // DIFF_RATIO
        sc = fmaxf(rr, 1e-6f);
        if (which == 0 && tid == 0) WS_RR(ws)[b] = rr;   // for final rr.mean()
    }

    // ---- exact-th filter of the conservative candidate set
    unsigned nraw = WS_CNT(ws)[b * 64];
    int ncons = (int)(nraw < (unsigned)CAP ? nraw : (unsigned)CAP);
    if (tid == 0) lk = 0;
    __syncthreads();
    for (int i = tid; i < ncons; i += 256) {
        float g = bufG[i];
        if (g < th) {
            unsigned p = atomicAdd(&lk, 1u);
            v[p] = bufN[i];
        }
    }
    __syncthreads();
    int n = (int)lk;
    int k = (int)floorf(0.6f * (float)n);   // (1-TRIM) in f32 — matches JAX promotion
    bool havek = (k > 0);

    if (havek) {
        unsigned selHi = 0;
        int rank = k - 1;
        for (int level = 0; level < 3; level++) {
            for (int i = tid; i < 4096; i += 256) hist[i] = 0;
            __syncthreads();
            for (int i = tid; i < n; i += 256) {
                unsigned key = __float_as_uint(v[i]);   // nonnegative -> order-monotone bits
                if (level == 0) {
                    atomicAdd(&hist[key >> 20], 1u);
                } else if (level == 1) {
                    if ((key >> 20) == selHi) atomicAdd(&hist[(key >> 8) & 0xFFFu], 1u);
                } else {
                    if ((key >> 8) == selHi) atomicAdd(&hist[key & 0xFFu], 1u);
                }
            }
            __syncthreads();
            int base = tid * 16;
            unsigned hloc[16];
            unsigned csum = 0;
#pragma unroll
            for (int j = 0; j < 16; j++) { hloc[j] = hist[base + j]; csum += hloc[j]; }
            unsigned incl = csum;
            for (int d = 1; d < 64; d <<= 1) {
                unsigned tshf = __shfl_up(incl, d);
                if (lane >= d) incl += tshf;
            }
            if (lane == 63) wtot[wid] = incl;
            __syncthreads();
            unsigned wadd = 0;
            for (int w = 0; w < wid; w++) wadd += wtot[w];
            incl += wadd;
            unsigned excl = incl - csum;
            if (rank >= (int)excl && rank < (int)incl) {
                unsigned cum = excl;
#pragma unroll
                for (int j = 0; j < 16; j++) {
                    unsigned h = hloc[j];
                    if ((unsigned)rank < cum + h) { sSel = (unsigned)(base + j); sRank = (unsigned)rank - cum; break; }
                    cum += h;
                }
            }
            __syncthreads();
            unsigned bin = sSel;
            rank = (int)sRank;
            if (level == 0) selHi = bin;
            else if (level == 1) selHi = (selHi << 12) | bin;
            else selHi = (selHi << 8) | bin;
        }
        unsigned Tkey = selHi;                  // exact bit pattern of k-th smallest numerator
        float T = __uint_as_float(Tkey);
        float sum = 0.0f;
        unsigned cnt = 0;
        for (int i = tid; i < n; i += 256) {
            float num = v[i];
            if (__float_as_uint(num) < Tkey) {
                float x = num / sc;
                sum += (x <= DELTAF) ? (0.5f * x * x / DELTAF) : (x - 0.5f * DELTAF);
                cnt++;
            }
        }
        for (int off = 32; off > 0; off >>= 1) {
            sum += __shfl_down(sum, off);
            cnt += __shfl_down(cnt, off);
        }
        if (lane == 0) { redf[wid] = sum; redc[wid] = cnt; }
        __syncthreads();
        if (tid == 0) {
            float tot = redf[0] + redf[1] + redf[2] + redf[3];
            unsigned c = redc[0] + redc[1] + redc[2] + redc[3];
            float xT = T / sc;
            float hubT = (xT <= DELTAF) ? (0.5f * xT * xT / DELTAF) : (xT - 0.5f * DELTAF);
            tot += (float)(k - (int)c) * hubT;
            lout[b] = tot / (float)k;
        }
    } else {
        if (tid == 0) lout[b] = 0.0f;
    }

    // ---- completion-counter finalize (replaces k7)
    if (tid == 0) {
        __threadfence();
        unsigned done = atomicAdd(WS_DONE(ws), 1u);
        if (done == 2u * NB - 1u) {
            __threadfence();
            float ld = 0.f, la = 0.f, rm = 0.f;
            for (int bb = 0; bb < NB; bb++) {
                ld += WS_LD(ws)[bb];
                la += WS_LA(ws)[bb];
                rm += WS_RR(ws)[bb];
            }
            ld *= (1.0f / 16.0f);
            la *= (1.0f / 16.0f);
            rm *= (1.0f / 16.0f);
            out[0] = ld + 0.2f * la;   // LAMBDA_ACCEL
            out[1] = ld;
            out[2] = la;
            out[3] = rm;
        }
    }
}

extern "C" void kernel_launch(void* const* d_in, const int* in_sizes, int n_in,
                              void* d_out, int out_size, void* d_ws, size_t ws_size,
                              hipStream_t stream) {
    (void)in_sizes; (void)n_in; (void)out_size; (void)ws_size;
    const float* pred = (const float*)d_in[0];
    const float* gt   = (const float*)d_in[1];
    const float* mask = (const float*)d_in[2];
    const float* prev = (const float*)d_in[3];
    float* out = (float*)d_out;
    unsigned char* ws = (unsigned char*)d_ws;

    hipMemsetAsync(ws, 0, ZERO_BYTES, stream);
    k1_sums_hist<<<dim3(60, 16), 256, 0, stream>>>(pred, gt, mask, ws);
    k2_rank1<<<16, 256, 0, stream>>>(ws);
    k5_elem<<<dim3(240, 16), 256, 0, stream>>>(pred, gt, mask, prev, out, ws);
    k6_huber<<<dim3(2, 16), 256, 0, stream>>>(out, ws);
}

// Round 7
// 192.409 us; speedup vs baseline: 1.0219x; 1.0219x over previous
//
#include <hip/hip_runtime.h>
#include <math.h>

// Problem constants (B=16, T=2, H=384, W=640)
#define NB   16
#define HW_  245760          // H*W
#define THW_ 491520          // 2*H*W
#define CAP  2048            // per-batch conservative compaction capacity (~1440 used)
#define BIGF 1e30f
#define DELTAF 0.03f
#define H1SLICES 8           // global L1-histogram slices (contention relief)

// ---- workspace layout (bytes) ----
#define SUMS_OFF   0u                                   // double[16*5]
#define HIST1_OFF  1024u                                // uint[16*8*4096] sliced
#define HIST2_OFF  (HIST1_OFF + NB*H1SLICES*4096u*4u)   // uint[16*4*4096]
#define CNT_OFF    (HIST2_OFF + NB*4u*4096u*4u)         // uint[16*64] (256B padded per batch)
#define DONE_OFF   (CNT_OFF + NB*256u)                  // uint[1] k6 completion counter
#define ZERO_BYTES (DONE_OFF + 64u)
#define PAR_OFF    ((ZERO_BYTES + 255u) & ~255u)
#define S_OFF      (PAR_OFF + 0u)      // float[16]
#define T_OFF      (PAR_OFF + 64u)     // float[16]
#define RR_OFF     (PAR_OFF + 128u)    // float[16]
#define NN_OFF     (PAR_OFF + 320u)    // int[16]
#define BIN_OFF    (PAR_OFF + 384u)    // int[16*4]
#define RK_OFF     (PAR_OFF + 640u)    // uint[16*4]
#define FR_OFF     (PAR_OFF + 896u)    // float[16*2]
#define LD_OFF     (PAR_OFF + 1024u)   // float[16]
#define LA_OFF     (PAR_OFF + 1088u)   // float[16]
#define THUB_OFF   (PAR_OFF + 1152u)   // float[16] conservative th upper bound
#define BUFD_OFF   (PAR_OFF + 2048u)   // float[16*CAP] |dpred-dgt|
#define BUFA_OFF   (BUFD_OFF + NB*CAP*4u)   // float[16*CAP] |dpred-prev|
#define BUFG_OFF   (BUFA_OFF + NB*CAP*4u)   // float[16*CAP] |dgt|

#define WS_SUMS(ws) ((double*)((ws) + SUMS_OFF))
#define WS_H1(ws)   ((unsigned*)((ws) + HIST1_OFF))
#define WS_H2(ws)   ((unsigned*)((ws) + HIST2_OFF))
#define WS_CNT(ws)  ((unsigned*)((ws) + CNT_OFF))      // index b*64
#define WS_DONE(ws) ((unsigned*)((ws) + DONE_OFF))
#define WS_S(ws)    ((float*)((ws) + S_OFF))
#define WS_T(ws)    ((float*)((ws) + T_OFF))
#define WS_RR(ws)   ((float*)((ws) + RR_OFF))
#define WS_NN(ws)   ((int*)((ws) + NN_OFF))
#define WS_BIN(ws)  ((int*)((ws) + BIN_OFF))
#define WS_RK(ws)   ((unsigned*)((ws) + RK_OFF))
#define WS_FR(ws)   ((float*)((ws) + FR_OFF))
#define WS_LD(ws)   ((float*)((ws) + LD_OFF))
#define WS_LA(ws)   ((float*)((ws) + LA_OFF))
#define WS_THUB(ws) ((float*)((ws) + THUB_OFF))
#define WS_BUFD(ws) ((float*)((ws) + BUFD_OFF))
#define WS_BUFA(ws) ((float*)((ws) + BUFA_OFF))
#define WS_BUFG(ws) ((float*)((ws) + BUFG_OFF))

// order-preserving float<->uint key
__device__ __forceinline__ unsigned fkey(float x) {
    unsigned u = __float_as_uint(x);
    return (u & 0x80000000u) ? ~u : (u | 0x80000000u);
}
__device__ __forceinline__ float keyf(unsigned k) {
    unsigned u = (k & 0x80000000u) ? (k & 0x7fffffffu) : ~k;
    return __uint_as_float(u);
}

// Block-cooperative rank locate in a 4096-bin histogram (256 threads).
__device__ void locate_ranks(const unsigned* __restrict__ hist, unsigned* part,
                             const int* ranks, int nr, int* outBin, unsigned* outOff) {
    int tid = threadIdx.x;
    int base = tid * 16;
    unsigned hloc[16];
    unsigned csum = 0;
#pragma unroll
    for (int j = 0; j < 16; j++) { hloc[j] = hist[base + j]; csum += hloc[j]; }
    part[tid] = csum;
    __syncthreads();
    for (int d = 1; d < 256; d <<= 1) {
        unsigned add = (tid >= d) ? part[tid - d] : 0u;
        __syncthreads();
        part[tid] += add;
        __syncthreads();
    }
    unsigned incl = part[tid];
    unsigned excl = incl - csum;
    for (int q = 0; q < nr; q++) {
        int r = ranks[q];
        if (r >= (int)excl && r < (int)incl) {
            unsigned cum = excl;
#pragma unroll
            for (int j = 0; j < 16; j++) {
                unsigned h = hloc[j];
                if ((unsigned)r < cum + h) { outBin[q] = base + j; outOff[q] = (unsigned)r - cum; break; }
                cum += h;
            }
        }
    }
    __syncthreads();
}

// K1: per-batch regression sums (f64) + level-1 (top-12-bit) histogram of masked gt.
// grid (30, 16), block 512: 16384 elements/block. Same total wave count as the
// 60x256 config (15 waves/CU) but HALF the per-block fixed cost (LDS zero +
// ~1500-atomic global flush) that dominates k1 (measured: T(60)=40us vs
// T(120)=51us => ~2.9us fixed/block).
__global__ __launch_bounds__(512) void k1_sums_hist(const float* __restrict__ pred,
                                                    const float* __restrict__ gt,
                                                    const float* __restrict__ mask,
                                                    unsigned char* ws) {
    __shared__ unsigned hist[8192];
    __shared__ double red[8][5];
    int tid = threadIdx.x;
    int b = blockIdx.y;
    unsigned half = (tid >> 5) & 1u;
    for (int i = tid; i < 8192; i += 512) hist[i] = 0;
    __syncthreads();

    size_t base = (size_t)b * THW_ + (size_t)blockIdx.x * 16384 + (size_t)tid * 4;
    double a00 = 0, a01 = 0, a11 = 0, sb0 = 0, sb1 = 0;
    float4 pc = *(const float4*)(pred + base);
    float4 gc = *(const float4*)(gt + base);
    float4 mc = *(const float4*)(mask + base);
#pragma unroll
    for (int it = 0; it < 8; it++) {
        float4 pn, gn, mn;
        if (it < 7) {
            size_t idx = base + (size_t)(it + 1) * 2048;
            pn = *(const float4*)(pred + idx);
            gn = *(const float4*)(gt + idx);
            mn = *(const float4*)(mask + idx);
        }
        float pa[4] = {pc.x, pc.y, pc.z, pc.w};
        float ga[4] = {gc.x, gc.y, gc.z, gc.w};
        float ma[4] = {mc.x, mc.y, mc.z, mc.w};
#pragma unroll
        for (int c = 0; c < 4; c++) {
            if (ma[c] > 0.5f) {
                float pv = pa[c], gv = ga[c];
                a00 += (double)(pv * pv);
                a01 += (double)pv;
                a11 += 1.0;
                sb0 += (double)(pv * gv);
                sb1 += (double)gv;
                atomicAdd(&hist[((fkey(gv) >> 20) << 1) | half], 1u);
            }
        }
        pc = pn; gc = gn; mc = mn;
    }
    __syncthreads();
    // flush nonzero bins to this block's slice, start rotated to spread lines
    unsigned* gh = WS_H1(ws) + ((size_t)b * H1SLICES + (blockIdx.x & (H1SLICES - 1))) * 4096u;
    unsigned rot = (blockIdx.x * 331u) & 4095u;
    for (int i = tid; i < 4096; i += 512) {
        int bin = (int)(((unsigned)i + rot) & 4095u);
        unsigned v = hist[bin * 2] + hist[bin * 2 + 1];
        if (v) atomicAdd(&gh[bin], v);
    }
    int lane = tid & 63, wid = tid >> 6;
    double acc[5] = {a00, a01, a11, sb0, sb1};
#pragma unroll
    for (int j = 0; j < 5; j++) {
        double v = acc[j];
        for (int off = 32; off > 0; off >>= 1) v += __shfl_down(v, off);
        if (lane == 0) red[wid][j] = v;
    }
    __syncthreads();
    if (tid == 0) {
        double* gs = WS_SUMS(ws) + b * 5;
#pragma unroll
        for (int j = 0; j < 5; j++) {
            double tot = 0.0;
#pragma unroll
            for (int w = 0; w < 8; w++) tot += red[w][j];
            atomicAdd(&gs[j], tot);
        }
    }
}

// K2: per-batch: s,t; sum the 8 H1 slices into LDS; quantile ranks; L1 bins; th_ub.
__global__ __launch_bounds__(256) void k2_rank1(unsigned char* ws) {
    __shared__ unsigned hsum[4096];
    __shared__ unsigned part[256];
    int b = blockIdx.x, tid = threadIdx.x;
    const double* gs = WS_SUMS(ws) + b * 5;
    double a00 = gs[0], a01 = gs[1], a11 = gs[2], b0 = gs[3], b1 = gs[4];
    int n = (int)(a11 + 0.5);
    if (tid == 0) {
        double det = a00 * a11 - a01 * a01;
        double x0 = 0.0, x1 = 0.0;
        if (det != 0.0) {
            x0 = (a11 * b0 - a01 * b1) / (det + 1e-6);
            x1 = (-a01 * b0 + a00 * b1) / (det + 1e-6);
        }
        WS_S(ws)[b] = (float)x0;
        WS_T(ws)[b] = (float)x1;
        WS_NN(ws)[b] = n;
    }
    // reduce slices: thread t owns bins [t*16, t*16+16)
    {
        const unsigned* h1 = WS_H1(ws) + (size_t)b * H1SLICES * 4096u;
        int base = tid * 16;
        unsigned acc[16];
#pragma unroll
        for (int j = 0; j < 16; j++) acc[j] = 0;
        for (int s = 0; s < H1SLICES; s++) {
            const unsigned* hs = h1 + (size_t)s * 4096u + base;
#pragma unroll
            for (int j = 0; j < 16; j++) acc[j] += hs[j];
        }
#pragma unroll
        for (int j = 0; j < 16; j++) hsum[base + j] = acc[j];
    }
    __syncthreads();
    float nm1 = (float)((n - 1 > 0) ? (n - 1) : 0);
    float p05 = 0.05f * nm1, p95 = 0.95f * nm1;   // f32 to match JAX weak-type promotion
    int ranks[4] = {(int)floorf(p05), (int)ceilf(p05), (int)floorf(p95), (int)ceilf(p95)};
    float f05 = p05 - floorf(p05), f95 = p95 - floorf(p95);
    if (tid == 0) {
        WS_FR(ws)[b * 2 + 0] = f05;
        WS_FR(ws)[b * 2 + 1] = f95;
    }
    if (n > 0) {
        locate_ranks(hsum, part, ranks, 4, WS_BIN(ws) + b * 4, WS_RK(ws) + b * 4);
        if (tid == 0) {
            const int* bp = WS_BIN(ws) + b * 4;
            float lb0 = keyf(((unsigned)bp[0]) << 20), ub0 = keyf((((unsigned)bp[0]) << 20) | 0xFFFFFu);
            float lb1 = keyf(((unsigned)bp[1]) << 20), ub1 = keyf((((unsigned)bp[1]) << 20) | 0xFFFFFu);
            float lb2 = keyf(((unsigned)bp[2]) << 20), ub2 = keyf((((unsigned)bp[2]) << 20) | 0xFFFFFu);
            float lb3 = keyf(((unsigned)bp[3]) << 20), ub3 = keyf((((unsigned)bp[3]) << 20) | 0xFFFFFu);
            float qlo_lb = (1.0f - f05) * lb0 + f05 * lb1;
            float qlo_ub = (1.0f - f05) * ub0 + f05 * ub1;
            float qhi_lb = (1.0f - f95) * lb2 + f95 * lb3;
            float qhi_ub = (1.0f - f95) * ub2 + f95 * ub3;
            float rr_ub = fmaxf(qhi_ub - qlo_lb, 1e-6f);
            if (qhi_lb - qlo_ub <= 0.0f) rr_ub = fmaxf(rr_ub, 1.0f);
            WS_THUB(ws)[b] = 0.01f * rr_ub * 1.0001f;   // tiny safety margin
        }
    } else if (tid == 0) {
        WS_THUB(ws)[b] = 0.0f;   // no masked pixels -> nothing static
        int* bp = WS_BIN(ws) + b * 4;
        bp[0] = bp[1] = bp[2] = bp[3] = -1;
    }
}

// K5: elementwise: dpred (-> curr_grad), conservative compact (numerators + |dgt|),
// and fused L2-histogram population for the 4 selected L1 bins (both frames).
// grid (240, 16), block 256; 1024 pixels per block.
__global__ __launch_bounds__(256) void k5_elem(const float* __restrict__ pred,
                                               const float* __restrict__ gt,
                                               const float* __restrict__ mask,
                                               const float* __restrict__ prev,
                                               float* __restrict__ out,
                                               unsigned char* ws) {
    __shared__ unsigned lcnt;
    __shared__ unsigned gbase;
    int b = blockIdx.y, tid = threadIdx.x;
    if (tid == 0) lcnt = 0;
    float s = WS_S(ws)[b], t = WS_T(ws)[b], thub = WS_THUB(ws)[b];
    const int* bp = WS_BIN(ws) + b * 4;
    int bn0 = bp[0], bn1 = bp[1], bn2 = bp[2], bn3 = bp[3];
    unsigned* h2 = WS_H2(ws);
    size_t hw = (size_t)blockIdx.x * 1024 + (size_t)tid * 4;
    size_t i0 = (size_t)b * THW_ + hw;
    size_t i1 = i0 + HW_;
    size_t ip = (size_t)b * HW_ + hw;
    float4 p0 = *(const float4*)(pred + i0);
    float4 p1 = *(const float4*)(pred + i1);
    float4 g0 = *(const float4*)(gt + i0);
    float4 g1 = *(const float4*)(gt + i1);
    float4 m0 = *(const float4*)(mask + i0);
    float4 m1 = *(const float4*)(mask + i1);
    float4 pv = *(const float4*)(prev + ip);
    float p0c[4] = {p0.x, p0.y, p0.z, p0.w};
    float p1c[4] = {p1.x, p1.y, p1.z, p1.w};
    float g0c[4] = {g0.x, g0.y, g0.z, g0.w};
    float g1c[4] = {g1.x, g1.y, g1.z, g1.w};
    float m0c[4] = {m0.x, m0.y, m0.z, m0.w};
    float m1c[4] = {m1.x, m1.y, m1.z, m1.w};
    float pvc[4] = {pv.x, pv.y, pv.z, pv.w};
    float dp[4], rd[4], ra[4], rg[4];
    int nst = 0;
    __syncthreads();   // lcnt=0 visible
#pragma unroll
    for (int c = 0; c < 4; c++) {
        float pa1 = s * p1c[c] + t;
        float pa0 = s * p0c[c] + t;
        float d = pa1 - pa0;
        dp[c] = d;
        float dg = g1c[c] - g0c[c];
        float adg = fabsf(dg);
        bool msk0 = m0c[c] > 0.5f, msk1 = m1c[c] > 0.5f;
        if (msk0 && msk1 && adg < thub) {
            rd[nst] = fabsf(d - dg);
            ra[nst] = fabsf(d - pvc[c]);
            rg[nst] = adg;
            nst++;
        }
        if (msk0) {
            unsigned key = fkey(g0c[c]);
            int top = (int)(key >> 20);
            unsigned sub = (key >> 8) & 0xFFFu;
            if (top == bn0) atomicAdd(&h2[(((size_t)b * 4 + 0) << 12) + sub], 1u);
            if (top == bn1) atomicAdd(&h2[(((size_t)b * 4 + 1) << 12) + sub], 1u);
            if (top == bn2) atomicAdd(&h2[(((size_t)b * 4 + 2) << 12) + sub], 1u);
            if (top == bn3) atomicAdd(&h2[(((size_t)b * 4 + 3) << 12) + sub], 1u);
        }
        if (msk1) {
            unsigned key = fkey(g1c[c]);
            int top = (int)(key >> 20);
            unsigned sub = (key >> 8) & 0xFFFu;
            if (top == bn0) atomicAdd(&h2[(((size_t)b * 4 + 0) << 12) + sub], 1u);
            if (top == bn1) atomicAdd(&h2[(((size_t)b * 4 + 1) << 12) + sub], 1u);
            if (top == bn2) atomicAdd(&h2[(((size_t)b * 4 + 2) << 12) + sub], 1u);
            if (top == bn3) atomicAdd(&h2[(((size_t)b * 4 + 3) << 12) + sub], 1u);
        }
    }
    unsigned myoff = 0;
    if (nst) myoff = atomicAdd(&lcnt, (unsigned)nst);   // LDS atomic — cheap
    __syncthreads();
    if (tid == 0 && lcnt > 0) gbase = atomicAdd(&WS_CNT(ws)[b * 64], lcnt);
    __syncthreads();
    if (nst) {
        float* bufd = WS_BUFD(ws) + (size_t)b * CAP;
        float* bufa = WS_BUFA(ws) + (size_t)b * CAP;
        float* bufg = WS_BUFG(ws) + (size_t)b * CAP;
        unsigned base0 = gbase + myoff;
        for (int j = 0; j < nst; j++) {
            unsigned pos = base0 + (unsigned)j;
            if (pos < CAP) { bufd[pos] = rd[j]; bufa[pos] = ra[j]; bufg[pos] = rg[j]; }
        }
    }
    float4 dout = make_float4(dp[0], dp[1], dp[2], dp[3]);
    *(float4*)(out + 4 + ip) = dout;
}

// K6: per (batch, which): exact rr from H2, exact-th filter, trimmed-Huber via
// 3-level radix select. Last block (completion counter) writes the 4 scalars.
// grid (2, 16), block 256.
__global__ __launch_bounds__(256) void k6_huber(float* __restrict__ out, unsigned char* ws) {
    __shared__ float v[CAP];
    __shared__ unsigned hist[4096];
    __shared__ unsigned part[256];
    __shared__ int ssub[4];
    __shared__ unsigned wtot[4];
    __shared__ unsigned sSel;
    __shared__ unsigned sRank;
    __shared__ float redf[4];
    __shared__ unsigned redc[4];
    __shared__ unsigned lk;
    int which = blockIdx.x, b = blockIdx.y, tid = threadIdx.x;
    int lane = tid & 63, wid = tid >> 6;
    const float* bufN = (which ? WS_BUFA(ws) : WS_BUFD(ws)) + (size_t)b * CAP;
    const float* bufG = WS_BUFG(ws) + (size_t)b * CAP;
    float* lout = which ? WS_LA(ws) : WS_LD(ws);

    // ---- exact quantile -> rr/th/sc (both which-blocks compute identically)
    int nmask = WS_NN(ws)[b];
    if (nmask > 0) {
        for (int q = 0; q < 4; q++) {
            int rq[1] = {(int)WS_RK(ws)[b * 4 + q]};
            unsigned dummyOff[1];
            locate_ranks(WS_H2(ws) + (((size_t)b * 4 + q) << 12), part, rq, 1, ssub + q, dummyOff);
        }
    }
    __syncthreads();
    float rr, th, sc;
    {
        float vals[4] = {0.f, 0.f, 0.f, 0.f};
        if (nmask > 0) {
            for (int q = 0; q < 4; q++) {
                unsigned key = (((unsigned)WS_BIN(ws)[b * 4 + q]) << 20) |
                               (((unsigned)ssub[q]) << 8) | 0x80u;   // mid of 256-ulp slot
                vals[q] = keyf(key);
            }
        }
        float f05 = WS_FR(ws)[b * 2 + 0], f95 = WS_FR(ws)[b * 2 + 1];
        float qlo = vals[0] + (vals[1] - vals[0]) * f05;
        float qhi = vals[2] + (vals[3] - vals[2]) * f95;
        bool valid = (nmask > 0) && isfinite(qlo) && isfinite(qhi) && (qhi - qlo > 0.0f) &&
                     (fabsf(qlo) < BIGF) && (fabsf(qhi) < BIGF);
        rr = valid ? fmaxf(qhi - qlo, 1e-6f) : 1.0f;
        th = 0.01f * rr;           // DIFF_RATIO
        sc = fmaxf(rr, 1e-6f);
        if (which == 0 && tid == 0) WS_RR(ws)[b] = rr;   // for final rr.mean()
    }

    // ---- exact-th filter of the conservative candidate set
    unsigned nraw = WS_CNT(ws)[b * 64];
    int ncons = (int)(nraw < (unsigned)CAP ? nraw : (unsigned)CAP);
    if (tid == 0) lk = 0;
    __syncthreads();
    for (int i = tid; i < ncons; i += 256) {
        float g = bufG[i];
        if (g < th) {
            unsigned p = atomicAdd(&lk, 1u);
            v[p] = bufN[i];
        }
    }
    __syncthreads();
    int n = (int)lk;
    int k = (int)floorf(0.6f * (float)n);   // (1-TRIM) in f32 — matches JAX promotion
    bool havek = (k > 0);

    if (havek) {
        unsigned selHi = 0;
        int rank = k - 1;
        for (int level = 0; level < 3; level++) {
            for (int i = tid; i < 4096; i += 256) hist[i] = 0;
            __syncthreads();
            for (int i = tid; i < n; i += 256) {
                unsigned key = __float_as_uint(v[i]);   // nonnegative -> order-monotone bits
                if (level == 0) {
                    atomicAdd(&hist[key >> 20], 1u);
                } else if (level == 1) {
                    if ((key >> 20) == selHi) atomicAdd(&hist[(key >> 8) & 0xFFFu], 1u);
                } else {
                    if ((key >> 8) == selHi) atomicAdd(&hist[key & 0xFFu], 1u);
                }
            }
            __syncthreads();
            int base = tid * 16;
            unsigned hloc[16];
            unsigned csum = 0;
#pragma unroll
            for (int j = 0; j < 16; j++) { hloc[j] = hist[base + j]; csum += hloc[j]; }
            unsigned incl = csum;
            for (int d = 1; d < 64; d <<= 1) {
                unsigned tshf = __shfl_up(incl, d);
                if (lane >= d) incl += tshf;
            }
            if (lane == 63) wtot[wid] = incl;
            __syncthreads();
            unsigned wadd = 0;
            for (int w = 0; w < wid; w++) wadd += wtot[w];
            incl += wadd;
            unsigned excl = incl - csum;
            if (rank >= (int)excl && rank < (int)incl) {
                unsigned cum = excl;
#pragma unroll
                for (int j = 0; j < 16; j++) {
                    unsigned h = hloc[j];
                    if ((unsigned)rank < cum + h) { sSel = (unsigned)(base + j); sRank = (unsigned)rank - cum; break; }
                    cum += h;
                }
            }
            __syncthreads();
            unsigned bin = sSel;
            rank = (int)sRank;
            if (level == 0) selHi = bin;
            else if (level == 1) selHi = (selHi << 12) | bin;
            else selHi = (selHi << 8) | bin;
        }
        unsigned Tkey = selHi;                  // exact bit pattern of k-th smallest numerator
        float T = __uint_as_float(Tkey);
        float sum = 0.0f;
        unsigned cnt = 0;
        for (int i = tid; i < n; i += 256) {
            float num = v[i];
            if (__float_as_uint(num) < Tkey) {
                float x = num / sc;
                sum += (x <= DELTAF) ? (0.5f * x * x / DELTAF) : (x - 0.5f * DELTAF);
                cnt++;
            }
        }
        for (int off = 32; off > 0; off >>= 1) {
            sum += __shfl_down(sum, off);
            cnt += __shfl_down(cnt, off);
        }
        if (lane == 0) { redf[wid] = sum; redc[wid] = cnt; }
        __syncthreads();
        if (tid == 0) {
            float tot = redf[0] + redf[1] + redf[2] + redf[3];
            unsigned c = redc[0] + redc[1] + redc[2] + redc[3];
            float xT = T / sc;
            float hubT = (xT <= DELTAF) ? (0.5f * xT * xT / DELTAF) : (xT - 0.5f * DELTAF);
            tot += (float)(k - (int)c) * hubT;
            lout[b] = tot / (float)k;
        }
    } else {
        if (tid == 0) lout[b] = 0.0f;
    }

    // ---- completion-counter finalize (replaces k7)
    if (tid == 0) {
        __threadfence();
        unsigned done = atomicAdd(WS_DONE(ws), 1u);
        if (done == 2u * NB - 1u) {
            __threadfence();
            float ld = 0.f, la = 0.f, rm = 0.f;
            for (int bb = 0; bb < NB; bb++) {
                ld += WS_LD(ws)[bb];
                la += WS_LA(ws)[bb];
                rm += WS_RR(ws)[bb];
            }
            ld *= (1.0f / 16.0f);
            la *= (1.0f / 16.0f);
            rm *= (1.0f / 16.0f);
            out[0] = ld + 0.2f * la;   // LAMBDA_ACCEL
            out[1] = ld;
            out[2] = la;
            out[3] = rm;
        }
    }
}

extern "C" void kernel_launch(void* const* d_in, const int* in_sizes, int n_in,
                              void* d_out, int out_size, void* d_ws, size_t ws_size,
                              hipStream_t stream) {
    (void)in_sizes; (void)n_in; (void)out_size; (void)ws_size;
    const float* pred = (const float*)d_in[0];
    const float* gt   = (const float*)d_in[1];
    const float* mask = (const float*)d_in[2];
    const float* prev = (const float*)d_in[3];
    float* out = (float*)d_out;
    unsigned char* ws = (unsigned char*)d_ws;

    hipMemsetAsync(ws, 0, ZERO_BYTES, stream);
    k1_sums_hist<<<dim3(30, 16), 512, 0, stream>>>(pred, gt, mask, ws);
    k2_rank1<<<16, 256, 0, stream>>>(ws);
    k5_elem<<<dim3(240, 16), 256, 0, stream>>>(pred, gt, mask, prev, out, ws);
    k6_huber<<<dim3(2, 16), 256, 0, stream>>>(out, ws);
}